// Round 9
// baseline (2040.995 us; speedup 1.0000x reference)
//
#include <hip/hip_runtime.h>
#include <math.h>

// DRL4TSP decode: B=512, F=2, N=128, H=256, 128 steps.
// R9: latency-hiding ILP. C/P7 restructured 8->4 outer iters: 6 weight b128
// loads (2 k-slices) issued up front, 4 scan h-iters (~140 cyc independent
// math) between issue and use, then both GEMV slices. Doubles outstanding
// L2 loads + load->use distance (true VALU occupancy ~35%; stalls ~55%).
// B unroll 4->8. Everything else identical to R8.

#define NB 512
#define NF 2
#define NN 128
#define NH 256
#define NH3 768
#define SC 2.8853900817779268f   // 2*log2(e): folds tanh doubling + exp->exp2

typedef float v2f __attribute__((ext_vector_type(2)));

__device__ __forceinline__ float fast_rcp(float x) { return __builtin_amdgcn_rcpf(x); }
__device__ __forceinline__ float fast_exp2(float x) { return __builtin_amdgcn_exp2f(x); }
__device__ __forceinline__ float sigm(float x) { return fast_rcp(1.0f + __expf(-x)); }
__device__ __forceinline__ float tanh_raw(float x) { return 1.0f - 2.0f * fast_rcp(1.0f + fast_exp2(SC * x)); }
__device__ __forceinline__ v2f vsplat(float a) { v2f r; r.x = a; r.y = a; return r; }
__device__ __forceinline__ v2f vfma(v2f a, v2f b, v2f c) { return __builtin_elementwise_fma(a, b, c); }

// ws layout (floats):
//   0     : Mgi[768] float2   (W_ih·Wdec, 2 cols interleaved)   [unscaled]
//   1536  : cgi[768]          (W_ih·bdec + b_ih)                [unscaled]
//   2304  : cA[256] float4    (SC*A_s0, SC*A_s1, SC*A_d1, -2*va)
//   3328  : a0[256]           (SC*(Wa_s·bs + Wa_d·(20*Wd0+bd)))
//   3584  : cP[256] float4    (SC*P_s0, SC*P_s1, -2*vp, 0)
//   5376  : WaH[256*256]      (SC*Wa[:,2H:3H] row-major)
//   70912 : cP2[256] float4   (SC*PC0, SC*PC1, SC*pb, 0)

__global__ void precompute_kernel(const float* __restrict__ Ws, const float* __restrict__ bs,
                                  const float* __restrict__ Wd, const float* __restrict__ bd,
                                  const float* __restrict__ Wdec, const float* __restrict__ bdec,
                                  const float* __restrict__ W_ih, const float* __restrict__ b_ih,
                                  const float* __restrict__ Wa, const float* __restrict__ va,
                                  const float* __restrict__ Wp, const float* __restrict__ vp,
                                  float* __restrict__ ws)
{
    int tid = blockIdx.x * blockDim.x + threadIdx.x;
    if (tid < 768) {                              // Mgi
        int j = tid; const float* wr = &W_ih[j * NH];
        float m0 = 0.f, m1 = 0.f;
        for (int k = 0; k < NH; k++) { float w = wr[k]; m0 = fmaf(w, Wdec[2*k], m0); m1 = fmaf(w, Wdec[2*k+1], m1); }
        ws[2*j] = m0; ws[2*j+1] = m1;
    } else if (tid < 1536) {                      // cgi
        int j = tid - 768; const float* wr = &W_ih[j * NH];
        float c = b_ih[j];
        for (int k = 0; k < NH; k++) c = fmaf(wr[k], bdec[k], c);
        ws[1536 + j] = c;
    } else if (tid < 1792) {                      // cA (SC-scaled; .w = -2*va)
        int h = tid - 1536; const float* war = &Wa[h * NH3];
        float as0 = 0.f, as1 = 0.f, ad1 = 0.f;
        for (int k = 0; k < NH; k++) {
            float w = war[k];
            as0 = fmaf(w, Ws[2*k], as0); as1 = fmaf(w, Ws[2*k+1], as1);
            ad1 = fmaf(war[NH + k], Wd[2*k+1], ad1);
        }
        float4 v = make_float4(SC*as0, SC*as1, SC*ad1, -2.0f*va[h]);
        ((float4*)(ws + 2304))[h] = v;
    } else if (tid < 2048) {                      // a0 (SC)
        int h = tid - 1792; const float* war = &Wa[h * NH3];
        float a = 0.f;
        for (int k = 0; k < NH; k++) {
            a = fmaf(war[k], bs[k], a);
            a = fmaf(war[NH + k], fmaf(20.0f, Wd[2*k], bd[k]), a);
        }
        ws[3328 + h] = SC * a;
    } else if (tid < 2304) {                      // cP (SC-scaled; .z = -2*vp)
        int h = tid - 2048; const float* wpr = &Wp[h * 2 * NH];
        float p0 = 0.f, p1 = 0.f;
        for (int k = 0; k < NH; k++) { float w = wpr[k]; p0 = fmaf(w, Ws[2*k], p0); p1 = fmaf(w, Ws[2*k+1], p1); }
        float4 v = make_float4(SC*p0, SC*p1, -2.0f*vp[h], 0.f);
        ((float4*)(ws + 3584))[h] = v;
    } else if (tid < 2560) {                      // cP2: SC*(PC0, PC1, pb)
        int h = tid - 2304;
        const float* wps = &Wp[h * 2 * NH];
        const float* wpc = wps + NH;
        float p0 = 0.f, p1 = 0.f, pb = 0.f;
        for (int k = 0; k < NH; k++) {
            p0 = fmaf(wpc[k], Ws[2*k], p0);
            p1 = fmaf(wpc[k], Ws[2*k+1], p1);
            pb = fmaf(wps[k] + wpc[k], bs[k], pb);
        }
        float4 v = make_float4(SC*p0, SC*p1, SC*pb, 0.f);
        ((float4*)(ws + 70912))[h] = v;
    } else if (tid < 2560 + 65536) {              // WaH pack (SC)
        int m = tid - 2560; int i = m >> 8, j = m & 255;
        ws[5376 + m] = SC * Wa[i * NH3 + 2 * NH + j];
    }
}

__global__ void __launch_bounds__(1024, 4)
drl_main(const float* __restrict__ gstatic, const float* __restrict__ gdyn,
         const float* __restrict__ glast, const float* __restrict__ gWhh,
         const float* __restrict__ gbhh, const float* __restrict__ wsb,
         float* __restrict__ out)
{
    __shared__ float s0[2][NN], s1[2][NN], d1[2][NN];
    __shared__ v2f hs2[NH];                // h interleaved over batch: (g0,g1)
    __shared__ float ghs[2][NH3];
    __shared__ float qp[2][NH];
    __shared__ float4 cA[NH];
    __shared__ float4 cP[NH];
    __shared__ float4 cP2[NH];
    __shared__ float2 Mgi[NH3];
    __shared__ float cgi[NH3], bhh[NH3];
    __shared__ float a0v[NH];
    __shared__ float spart[2][NN * 20];    // 16 scan partials per n, stride 20
    __shared__ float gpart[384 * 20];      // GEMV partials: [row][kq*2+g], stride 20
    __shared__ float Sw[2][2];
    __shared__ int idxs[2];

    const int t = threadIdx.x;
    const int g = t >> 9;          // batch elem within block
    const int r = t & 511;
    const int b0 = blockIdx.x * 2;

    // ---- stage inputs + coefficients into LDS
    for (int i = t; i < 2 * NN; i += 1024) {
        int gg = i >> 7, n = i & 127, b = b0 + gg;
        s0[gg][n] = gstatic[b * (NF * NN) + n];
        s1[gg][n] = gstatic[b * (NF * NN) + NN + n];
        d1[gg][n] = gdyn[b * (NF * NN) + NN + n];
    }
    for (int i = t; i < 2 * NH; i += 1024) {
        int gg = i >> 8, j = i & 255;
        ((float*)hs2)[2 * j + gg] = glast[(b0 + gg) * NH + j];
    }
    for (int i = t; i < 1536; i += 1024) ((float*)Mgi)[i] = wsb[i];
    if (t < 768) cgi[t] = wsb[1536 + t];
    if (t < 1024) ((float*)cA)[t] = wsb[2304 + t];
    if (t < 256) a0v[t] = wsb[3328 + t];
    if (t < 1024) ((float*)cP)[t] = wsb[3584 + t];
    if (t < 1024) ((float*)cP2)[t] = wsb[70912 + t];
    if (t < 768) bhh[t] = gbhh[t];
    if (t == 0) { idxs[0] = 0; idxs[1] = 0; }
    __syncthreads();

    const float* WaH = wsb + 5376;
    const int jb = t >> 3, kq = t & 7;     // fused-GEMV tiling: 128 rows, 8-way k-split
    const int jb2 = t >> 2, kh = t & 3;    // qp GEMV tiling: 256 rows, 4-way k-split

    // scan tiling: thread owns h-set {hg + 16*hl, hl<16}, n-quad {n0..n0+3} as 2 pairs
    const int ng = r >> 4, hg = r & 15;
    const int n0 = ng * 4;
    v2f sa0, sa1, da, sb0, sb1, db;
    sa0.x = s0[g][n0];     sa0.y = s0[g][n0 + 1];
    sa1.x = s1[g][n0];     sa1.y = s1[g][n0 + 1];
    da.x  = d1[g][n0];     da.y  = d1[g][n0 + 1];
    sb0.x = s0[g][n0 + 2]; sb0.y = s0[g][n0 + 3];
    sb1.x = s1[g][n0 + 2]; sb1.y = s1[g][n0 + 3];
    db.x  = d1[g][n0 + 2]; db.y  = d1[g][n0 + 3];
    float cwsum, vpsum;
    {
        float cw = 0.f, vq = 0.f;
        #pragma unroll 8
        for (int hl = 0; hl < 16; hl++) {
            cw += cA[hg + 16 * hl].w;
            vq += cP[hg + 16 * hl].z;
        }
        cwsum = -0.5f * cw; vpsum = -0.5f * vq;   // = sum(va), sum(vp) over h-set
    }

    // ---- initial gh = W_hh*last_hh + b_hh (768 rows, 8-way k-split, batch-packed)
    {
        v2f acc[6];
        #pragma unroll
        for (int i = 0; i < 6; i++) { acc[i].x = 0.f; acc[i].y = 0.f; }
        const float* wb = gWhh + jb * NH + 4 * kq;
        #pragma unroll 2
        for (int c = 0; c < 8; c++) {
            float4 p01 = *(const float4*)&((float*)hs2)[2 * (32 * c + 4 * kq)];
            float4 p23 = *(const float4*)&((float*)hs2)[2 * (32 * c + 4 * kq) + 4];
            v2f hk0, hk1, hk2, hk3;
            hk0.x = p01.x; hk0.y = p01.y; hk1.x = p01.z; hk1.y = p01.w;
            hk2.x = p23.x; hk2.y = p23.y; hk3.x = p23.z; hk3.y = p23.w;
            #pragma unroll
            for (int p = 0; p < 6; p++) {
                float4 w = *(const float4*)(wb + p * 128 * NH + 32 * c);
                acc[p] = vfma(vsplat(w.x), hk0, vfma(vsplat(w.y), hk1,
                         vfma(vsplat(w.z), hk2, vfma(vsplat(w.w), hk3, acc[p]))));
            }
        }
        #pragma unroll
        for (int p = 0; p < 6; p++) {
            float u0 = acc[p].x, u1 = acc[p].y;
            u0 += __shfl_xor(u0, 1); u0 += __shfl_xor(u0, 2); u0 += __shfl_xor(u0, 4);
            u1 += __shfl_xor(u1, 1); u1 += __shfl_xor(u1, 2); u1 += __shfl_xor(u1, 4);
            if (kq == 0) { int j = jb + 128 * p; ghs[0][j] = u0 + bhh[j]; ghs[1][j] = u1 + bhh[j]; }
        }
    }
    __syncthreads();

    for (int step = 0; step < NN; step++) {
        // ---- P2: GRU elementwise (512 of 1024 threads active)
        if (r < 256) {
            int id = idxs[g];
            float svA = s0[g][id], svB = s1[g][id];
            float2 m0 = Mgi[r], m1 = Mgi[NH + r], m2 = Mgi[2 * NH + r];
            float ir  = fmaf(m0.x, svA, fmaf(m0.y, svB, cgi[r]));
            float iz  = fmaf(m1.x, svA, fmaf(m1.y, svB, cgi[NH + r]));
            float inn = fmaf(m2.x, svA, fmaf(m2.y, svB, cgi[2 * NH + r]));
            float rr = sigm(ir + ghs[g][r]);
            float zz = sigm(iz + ghs[g][NH + r]);
            float nv = tanh_raw(fmaf(rr, ghs[g][2 * NH + r], inn));
            float ho = ((float*)hs2)[2 * r + g];
            ((float*)hs2)[2 * r + g] = fmaf(zz, ho - nv, nv);
        }
        __syncthreads();
        // ---- B: qp = SC*Wa_h*h + a0  (256 rows, 4-way k-split, batch-packed)
        {
            v2f u; u.x = 0.f; u.y = 0.f;
            const float* wq = WaH + jb2 * NH + 4 * kh;
            #pragma unroll 8
            for (int ks = 0; ks < 16; ks++) {
                float4 w  = *(const float4*)(wq + ks * 16);
                float4 p01 = *(const float4*)&((float*)hs2)[2 * (ks * 16 + 4 * kh)];
                float4 p23 = *(const float4*)&((float*)hs2)[2 * (ks * 16 + 4 * kh) + 4];
                v2f hk0, hk1, hk2, hk3;
                hk0.x = p01.x; hk0.y = p01.y; hk1.x = p01.z; hk1.y = p01.w;
                hk2.x = p23.x; hk2.y = p23.y; hk3.x = p23.z; hk3.y = p23.w;
                u = vfma(vsplat(w.x), hk0, vfma(vsplat(w.y), hk1,
                    vfma(vsplat(w.z), hk2, vfma(vsplat(w.w), hk3, u))));
            }
            u.x += __shfl_xor(u.x, 1); u.x += __shfl_xor(u.x, 2);
            u.y += __shfl_xor(u.y, 1); u.y += __shfl_xor(u.y, 2);
            if (kh == 0) { qp[0][jb2] = u.x + a0v[jb2]; qp[1][jb2] = u.y + a0v[jb2]; }
        }
        __syncthreads();
        // ---- C: fused W_hh rows [0,384) GEMV + attention scan
        // 4 outer iters: 6 weight b128 in flight, 4 scan h-iters between issue and use
        {
            v2f at_a = vsplat(cwsum), at_b = vsplat(cwsum);
            v2f g0, g1, g2;
            g0.x = 0.f; g0.y = 0.f; g1.x = 0.f; g1.y = 0.f; g2.x = 0.f; g2.y = 0.f;
            const float* wb = gWhh + jb * NH + 4 * kq;
            #pragma unroll 1
            for (int ks = 0; ks < 4; ks++) {
                // two k-slices: 2ks and 2ks+1 (offsets 64*ks and 64*ks+32)
                float4 wA0 = *(const float4*)(wb + 0 * 128 * NH + ks * 64);
                float4 wA1 = *(const float4*)(wb + 1 * 128 * NH + ks * 64);
                float4 wA2 = *(const float4*)(wb + 2 * 128 * NH + ks * 64);
                float4 wB0 = *(const float4*)(wb + 0 * 128 * NH + ks * 64 + 32);
                float4 wB1 = *(const float4*)(wb + 1 * 128 * NH + ks * 64 + 32);
                float4 wB2 = *(const float4*)(wb + 2 * 128 * NH + ks * 64 + 32);
                // 4 scan h-iters of independent math while loads are in flight
                #pragma unroll
                for (int u = 0; u < 4; u++) {
                    int h = hg + 16 * (4 * ks + u);
                    float4 c4 = cA[h];
                    float qv = qp[g][h];
                    v2f xa = vfma(vsplat(c4.x), sa0, vfma(vsplat(c4.y), sa1,
                             vfma(vsplat(c4.z), da, vsplat(qv))));
                    v2f xb = vfma(vsplat(c4.x), sb0, vfma(vsplat(c4.y), sb1,
                             vfma(vsplat(c4.z), db, vsplat(qv))));
                    v2f ea, eb;
                    ea.x = fast_exp2(xa.x); ea.y = fast_exp2(xa.y);
                    eb.x = fast_exp2(xb.x); eb.y = fast_exp2(xb.y);
                    v2f ta = ea + 1.0f, tb = eb + 1.0f;
                    float pa = ta.x * ta.y, pb = tb.x * tb.y;
                    float rd = fast_rcp(pa * pb);
                    float m = c4.w * rd;                 // c4.w = -2*va
                    at_a = vfma(vsplat(m * pb), ta.yx, at_a);
                    at_b = vfma(vsplat(m * pa), tb.yx, at_b);
                }
                // GEMV for both k-slices
                float4 pA01 = *(const float4*)&((float*)hs2)[2 * (ks * 64 + 4 * kq)];
                float4 pA23 = *(const float4*)&((float*)hs2)[2 * (ks * 64 + 4 * kq) + 4];
                float4 pB01 = *(const float4*)&((float*)hs2)[2 * (ks * 64 + 32 + 4 * kq)];
                float4 pB23 = *(const float4*)&((float*)hs2)[2 * (ks * 64 + 32 + 4 * kq) + 4];
                v2f a0k, a1k, a2k, a3k, b0k, b1k, b2k, b3k;
                a0k.x = pA01.x; a0k.y = pA01.y; a1k.x = pA01.z; a1k.y = pA01.w;
                a2k.x = pA23.x; a2k.y = pA23.y; a3k.x = pA23.z; a3k.y = pA23.w;
                b0k.x = pB01.x; b0k.y = pB01.y; b1k.x = pB01.z; b1k.y = pB01.w;
                b2k.x = pB23.x; b2k.y = pB23.y; b3k.x = pB23.z; b3k.y = pB23.w;
                g0 = vfma(vsplat(wA0.x), a0k, vfma(vsplat(wA0.y), a1k,
                     vfma(vsplat(wA0.z), a2k, vfma(vsplat(wA0.w), a3k, g0))));
                g1 = vfma(vsplat(wA1.x), a0k, vfma(vsplat(wA1.y), a1k,
                     vfma(vsplat(wA1.z), a2k, vfma(vsplat(wA1.w), a3k, g1))));
                g2 = vfma(vsplat(wA2.x), a0k, vfma(vsplat(wA2.y), a1k,
                     vfma(vsplat(wA2.z), a2k, vfma(vsplat(wA2.w), a3k, g2))));
                g0 = vfma(vsplat(wB0.x), b0k, vfma(vsplat(wB0.y), b1k,
                     vfma(vsplat(wB0.z), b2k, vfma(vsplat(wB0.w), b3k, g0))));
                g1 = vfma(vsplat(wB1.x), b0k, vfma(vsplat(wB1.y), b1k,
                     vfma(vsplat(wB1.z), b2k, vfma(vsplat(wB1.w), b3k, g1))));
                g2 = vfma(vsplat(wB2.x), b0k, vfma(vsplat(wB2.y), b1k,
                     vfma(vsplat(wB2.z), b2k, vfma(vsplat(wB2.w), b3k, g2))));
            }
            spart[g][(n0 + 0) * 20 + hg] = at_a.x;
            spart[g][(n0 + 1) * 20 + hg] = at_a.y;
            spart[g][(n0 + 2) * 20 + hg] = at_b.x;
            spart[g][(n0 + 3) * 20 + hg] = at_b.y;
            *(v2f*)&gpart[(jb      ) * 20 + (kq << 1)] = g0;
            *(v2f*)&gpart[(jb + 128) * 20 + (kq << 1)] = g1;
            *(v2f*)&gpart[(jb + 256) * 20 + (kq << 1)] = g2;
        }
        __syncthreads();
        // ---- P5: ghs[0,384) reduction (idle threads) + softmax (fused butterfly)
        {
            int v = t - 64;
            if (t >= 64 && v < 384) {
                const float* gp = &gpart[v * 20];
                float4 q0 = *(const float4*)(gp);
                float4 q1 = *(const float4*)(gp + 4);
                float4 q2 = *(const float4*)(gp + 8);
                float4 q3 = *(const float4*)(gp + 12);
                float sg0 = ((q0.x + q0.z) + (q1.x + q1.z)) + ((q2.x + q2.z) + (q3.x + q3.z));
                float sg1 = ((q0.y + q0.w) + (q1.y + q1.w)) + ((q2.y + q2.w) + (q3.y + q3.w));
                ghs[0][v] = sg0 + bhh[v];
                ghs[1][v] = sg1 + bhh[v];
            }
            if (r < 64) {
                int l = r;
                const float* sp0 = &spart[g][l * 20];
                const float* sp1 = &spart[g][(l + 64) * 20];
                float4 q0 = *(const float4*)(sp0), q1 = *(const float4*)(sp0 + 4);
                float4 q2 = *(const float4*)(sp0 + 8), q3 = *(const float4*)(sp0 + 12);
                float v0 = ((q0.x+q0.y)+(q0.z+q0.w)) + ((q1.x+q1.y)+(q1.z+q1.w))
                         + ((q2.x+q2.y)+(q2.z+q2.w)) + ((q3.x+q3.y)+(q3.z+q3.w));
                q0 = *(const float4*)(sp1); q1 = *(const float4*)(sp1 + 4);
                q2 = *(const float4*)(sp1 + 8); q3 = *(const float4*)(sp1 + 12);
                float v1 = ((q0.x+q0.y)+(q0.z+q0.w)) + ((q1.x+q1.y)+(q1.z+q1.w))
                         + ((q2.x+q2.y)+(q2.z+q2.w)) + ((q3.x+q3.y)+(q3.z+q3.w));
                // |logits| <= sum|va| ~ 10 -> exp safe without max-subtract
                float e0 = __expf(v0), e1 = __expf(v1);
                float aa = e0 + e1;
                float bb = fmaf(e0, s0[g][l], e1 * s0[g][l + 64]);
                float cc = fmaf(e0, s1[g][l], e1 * s1[g][l + 64]);
                #pragma unroll
                for (int o = 32; o; o >>= 1) {
                    aa += __shfl_xor(aa, o);
                    bb += __shfl_xor(bb, o);
                    cc += __shfl_xor(cc, o);
                }
                if (l == 0) {
                    float rs = fast_rcp(aa);
                    Sw[g][0] = bb * rs; Sw[g][1] = cc * rs;
                }
            }
        }
        __syncthreads();
        // ---- P7: fused W_hh rows [384,768) GEMV + pointer scan (same ILP shape)
        {
            float S0 = Sw[g][0], S1 = Sw[g][1];
            v2f at_a = vsplat(vpsum), at_b = vsplat(vpsum);
            v2f g0, g1, g2;
            g0.x = 0.f; g0.y = 0.f; g1.x = 0.f; g1.y = 0.f; g2.x = 0.f; g2.y = 0.f;
            const float* wb = gWhh + (384 + jb) * NH + 4 * kq;
            #pragma unroll 1
            for (int ks = 0; ks < 4; ks++) {
                float4 wA0 = *(const float4*)(wb + 0 * 128 * NH + ks * 64);
                float4 wA1 = *(const float4*)(wb + 1 * 128 * NH + ks * 64);
                float4 wA2 = *(const float4*)(wb + 2 * 128 * NH + ks * 64);
                float4 wB0 = *(const float4*)(wb + 0 * 128 * NH + ks * 64 + 32);
                float4 wB1 = *(const float4*)(wb + 1 * 128 * NH + ks * 64 + 32);
                float4 wB2 = *(const float4*)(wb + 2 * 128 * NH + ks * 64 + 32);
                #pragma unroll
                for (int u = 0; u < 4; u++) {
                    int h = hg + 16 * (4 * ks + u);
                    float4 c4 = cP[h];
                    float4 c2 = cP2[h];
                    float pc = fmaf(c2.x, S0, fmaf(c2.y, S1, c2.z));
                    v2f xa = vfma(vsplat(c4.x), sa0, vfma(vsplat(c4.y), sa1, vsplat(pc)));
                    v2f xb = vfma(vsplat(c4.x), sb0, vfma(vsplat(c4.y), sb1, vsplat(pc)));
                    v2f ea, eb;
                    ea.x = fast_exp2(xa.x); ea.y = fast_exp2(xa.y);
                    eb.x = fast_exp2(xb.x); eb.y = fast_exp2(xb.y);
                    v2f ta = ea + 1.0f, tb = eb + 1.0f;
                    float pa = ta.x * ta.y, pb = tb.x * tb.y;
                    float rd = fast_rcp(pa * pb);
                    float m = c4.z * rd;                 // c4.z = -2*vp
                    at_a = vfma(vsplat(m * pb), ta.yx, at_a);
                    at_b = vfma(vsplat(m * pa), tb.yx, at_b);
                }
                float4 pA01 = *(const float4*)&((float*)hs2)[2 * (ks * 64 + 4 * kq)];
                float4 pA23 = *(const float4*)&((float*)hs2)[2 * (ks * 64 + 4 * kq) + 4];
                float4 pB01 = *(const float4*)&((float*)hs2)[2 * (ks * 64 + 32 + 4 * kq)];
                float4 pB23 = *(const float4*)&((float*)hs2)[2 * (ks * 64 + 32 + 4 * kq) + 4];
                v2f a0k, a1k, a2k, a3k, b0k, b1k, b2k, b3k;
                a0k.x = pA01.x; a0k.y = pA01.y; a1k.x = pA01.z; a1k.y = pA01.w;
                a2k.x = pA23.x; a2k.y = pA23.y; a3k.x = pA23.z; a3k.y = pA23.w;
                b0k.x = pB01.x; b0k.y = pB01.y; b1k.x = pB01.z; b1k.y = pB01.w;
                b2k.x = pB23.x; b2k.y = pB23.y; b3k.x = pB23.z; b3k.y = pB23.w;
                g0 = vfma(vsplat(wA0.x), a0k, vfma(vsplat(wA0.y), a1k,
                     vfma(vsplat(wA0.z), a2k, vfma(vsplat(wA0.w), a3k, g0))));
                g1 = vfma(vsplat(wA1.x), a0k, vfma(vsplat(wA1.y), a1k,
                     vfma(vsplat(wA1.z), a2k, vfma(vsplat(wA1.w), a3k, g1))));
                g2 = vfma(vsplat(wA2.x), a0k, vfma(vsplat(wA2.y), a1k,
                     vfma(vsplat(wA2.z), a2k, vfma(vsplat(wA2.w), a3k, g2))));
                g0 = vfma(vsplat(wB0.x), b0k, vfma(vsplat(wB0.y), b1k,
                     vfma(vsplat(wB0.z), b2k, vfma(vsplat(wB0.w), b3k, g0))));
                g1 = vfma(vsplat(wB1.x), b0k, vfma(vsplat(wB1.y), b1k,
                     vfma(vsplat(wB1.z), b2k, vfma(vsplat(wB1.w), b3k, g1))));
                g2 = vfma(vsplat(wB2.x), b0k, vfma(vsplat(wB2.y), b1k,
                     vfma(vsplat(wB2.z), b2k, vfma(vsplat(wB2.w), b3k, g2))));
            }
            spart[g][(n0 + 0) * 20 + hg] = at_a.x;
            spart[g][(n0 + 1) * 20 + hg] = at_a.y;
            spart[g][(n0 + 2) * 20 + hg] = at_b.x;
            spart[g][(n0 + 3) * 20 + hg] = at_b.y;
            *(v2f*)&gpart[(jb      ) * 20 + (kq << 1)] = g0;
            *(v2f*)&gpart[(jb + 128) * 20 + (kq << 1)] = g1;
            *(v2f*)&gpart[(jb + 256) * 20 + (kq << 1)] = g2;
        }
        __syncthreads();
        // ---- P8: ghs[384,768) reduction (idle threads) + argmax (fused butterfly)
        {
            int v = t - 64;
            if (t >= 64 && v < 384) {
                const float* gp = &gpart[v * 20];
                float4 q0 = *(const float4*)(gp);
                float4 q1 = *(const float4*)(gp + 4);
                float4 q2 = *(const float4*)(gp + 8);
                float4 q3 = *(const float4*)(gp + 12);
                float sg0 = ((q0.x + q0.z) + (q1.x + q1.z)) + ((q2.x + q2.z) + (q3.x + q3.z));
                float sg1 = ((q0.y + q0.w) + (q1.y + q1.w)) + ((q2.y + q2.w) + (q3.y + q3.w));
                ghs[0][384 + v] = sg0 + bhh[384 + v];
                ghs[1][384 + v] = sg1 + bhh[384 + v];
            }
            if (r < 64) {
                int l = r;
                const float* sp0 = &spart[g][l * 20];
                const float* sp1 = &spart[g][(l + 64) * 20];
                float4 q0 = *(const float4*)(sp0), q1 = *(const float4*)(sp0 + 4);
                float4 q2 = *(const float4*)(sp0 + 8), q3 = *(const float4*)(sp0 + 12);
                float v0 = ((q0.x+q0.y)+(q0.z+q0.w)) + ((q1.x+q1.y)+(q1.z+q1.w))
                         + ((q2.x+q2.y)+(q2.z+q2.w)) + ((q3.x+q3.y)+(q3.z+q3.w));
                q0 = *(const float4*)(sp1); q1 = *(const float4*)(sp1 + 4);
                q2 = *(const float4*)(sp1 + 8); q3 = *(const float4*)(sp1 + 12);
                float v1 = ((q0.x+q0.y)+(q0.z+q0.w)) + ((q1.x+q1.y)+(q1.z+q1.w))
                         + ((q2.x+q2.y)+(q2.z+q2.w)) + ((q3.x+q3.y)+(q3.z+q3.w));
                float bv = v0; int bi = l;
                if (v1 > v0) { bv = v1; bi = l + 64; }
                float es = __expf(v0) + __expf(v1);    // unnormalized; |v| <= ~10
                #pragma unroll
                for (int o = 32; o; o >>= 1) {
                    float ov = __shfl_xor(bv, o); int oi = __shfl_xor(bi, o);
                    es += __shfl_xor(es, o);
                    if (ov > bv || (ov == bv && oi < bi)) { bv = ov; bi = oi; }
                }
                if (l == 0) {
                    idxs[g] = bi;
                    int b = b0 + g;
                    out[b * NN + step] = (float)bi;
                    out[NB * NN + b * NN + step] = bv - logf(es);  // = -log(sum exp(v-bv))
                }
            }
        }
        __syncthreads();
    }
}

extern "C" void kernel_launch(void* const* d_in, const int* in_sizes, int n_in,
                              void* d_out, int out_size, void* d_ws, size_t ws_size,
                              hipStream_t stream) {
    const float* gstatic = (const float*)d_in[0];
    const float* gdyn    = (const float*)d_in[1];
    const float* glast   = (const float*)d_in[2];
    const float* Ws      = (const float*)d_in[3];
    const float* bs      = (const float*)d_in[4];
    const float* Wd      = (const float*)d_in[5];
    const float* bd      = (const float*)d_in[6];
    const float* Wdec    = (const float*)d_in[7];
    const float* bdec    = (const float*)d_in[8];
    const float* W_ih    = (const float*)d_in[9];
    const float* W_hh    = (const float*)d_in[10];
    const float* b_ih    = (const float*)d_in[11];
    const float* b_hh    = (const float*)d_in[12];
    const float* Wa      = (const float*)d_in[13];
    const float* va      = (const float*)d_in[14];
    const float* Wp      = (const float*)d_in[15];
    const float* vp      = (const float*)d_in[16];
    float* outp = (float*)d_out;
    float* wsb  = (float*)d_ws;

    precompute_kernel<<<267, 256, 0, stream>>>(Ws, bs, Wd, bd, Wdec, bdec,
                                               W_ih, b_ih, Wa, va, Wp, vp, wsb);
    drl_main<<<256, 1024, 0, stream>>>(gstatic, gdyn, glast, W_hh, b_hh, wsb, outp);
}